// Round 14
// baseline (128.275 us; speedup 1.0000x reference)
//
#include <hip/hip_runtime.h>

typedef unsigned long long u64;
typedef unsigned int u32;

#define BDIM 16
#define NP   4096
#define NC   91
#define NCM1 90
#define MSEL 4096       // top-M per image (reference M)
#define NSORT 1024      // batch-0 sorted prefix size
#define KOUT 100
#define RSLOT 19        // max candidates per row (scores sum to 1, >0.05 => <=19)
#define CAP_D (NP * RSLOT)   // 77824: provable per-image max -> no overflow possible
#define SCORE_T 0.05f
#define NMS_T   0.5f
#define OFFSETF 10000.0f
#define DW_CLAMP_F 4.135166556742356f
#define WF 1333.0f
#define HF 800.0f

#define TN 1024
#define NW (TN / 64)      // 16 waves
#define RPB 64            // rows per k_soft block (64 blocks per image)
#define AMAX (KOUT + 64)

// decode expressions (round-6..13 verified, byte-identical), emitted as a macro so
// k_decode and k_walk-fallback share the exact same text.
#define DECODE_BODY(kvar, bvar, BOXDST, PACKDST)                                   \
    {                                                                              \
        int flat = (int)(~(u32)(kvar));                                            \
        int nidx = flat / NCM1;                                                    \
        int c    = flat - nidx * NCM1 + 1;                                         \
        const float* pr = props + ((long)(bvar) * NP + nidx) * 4;                  \
        float x1 = pr[0], y1 = pr[1], x2 = pr[2], y2 = pr[3];                      \
        float w = x2 - x1, h = y2 - y1;                                            \
        float cx = x1 + 0.5f * w, cy = y1 + 0.5f * h;                              \
        const float* rr = boxreg + (((long)(bvar) * NP + nidx) * NC + c) * 4;      \
        float dx = rr[0] / 10.0f, dy = rr[1] / 10.0f;                              \
        float dw = fminf(rr[2] / 5.0f, DW_CLAMP_F);                                \
        float dh = fminf(rr[3] / 5.0f, DW_CLAMP_F);                                \
        float pcx = __fadd_rn(__fmul_rn(dx, w), cx);                               \
        float pcy = __fadd_rn(__fmul_rn(dy, h), cy);                               \
        float pw  = __fmul_rn(expf(dw), w);                                        \
        float ph2 = __fmul_rn(expf(dh), h);                                        \
        float bx1 = fminf(fmaxf(pcx - 0.5f * pw, 0.0f), WF);                       \
        float by1 = fminf(fmaxf(pcy - 0.5f * ph2, 0.0f), HF);                      \
        float bx2 = fminf(fmaxf(pcx + 0.5f * pw, 0.0f), WF);                       \
        float by2 = fminf(fmaxf(pcy + 0.5f * ph2, 0.0f), HF);                      \
        BOXDST = make_float4(bx1, by1, bx2, by2);                                  \
        float offB = (float)c * OFFSETF;                                           \
        float ox1 = bx1 + offB, oy1 = by1 + offB;                                  \
        float ox2 = bx2 + offB, oy2 = by2 + offB;                                  \
        PACKDST = make_float2((ox2 - ox1) * (oy2 - oy1), (float)c);                \
    }

// ---------------- Kernel 0: zero the 16 per-image counters ----------------
__global__ __launch_bounds__(64) void k_zero(int* __restrict__ gcount) {
    if (threadIdx.x < BDIM) gcount[threadIdx.x] = 0;
}

// ---------------- Kernel 1: softmax -> dense candidates (round-10/12 verified) ----------------
__global__ __launch_bounds__(256) void k_soft(const float* __restrict__ logits,
                                              u64* __restrict__ dense,
                                              int* __restrict__ gcount) {
    __shared__ u64 stage[RPB * RSLOT];
    __shared__ int s_cnt, s_base;

    int blk  = blockIdx.x;
    int b    = blk >> 6;
    int lane = threadIdx.x & 63;
    int wid  = threadIdx.x >> 6;

    if (threadIdx.x == 0) s_cnt = 0;
    __syncthreads();

    u64 lm = (1ull << lane) - 1ull;
    for (int it = 0; it < RPB / 4; ++it) {
        int row = blk * RPB + it * 4 + wid;
        const float* lg = logits + (long)row * NC;

        float v0 = lg[lane];
        float v1 = (lane < NC - 64) ? lg[64 + lane] : -3.0e38f;
        float mx = fmaxf(v0, v1);
#pragma unroll
        for (int s = 32; s; s >>= 1) mx = fmaxf(mx, __shfl_xor(mx, s));
        float e0 = expf(v0 - mx);
        float e1 = (lane < NC - 64) ? expf(v1 - mx) : 0.0f;
        float sum = e0 + e1;
#pragma unroll
        for (int s = 32; s; s >>= 1) sum += __shfl_xor(sum, s);

        float s0 = e0 / sum;
        float s1 = e1 / sum;

        int n = row & (NP - 1);
        bool p0 = (lane >= 1) && (s0 > SCORE_T);
        bool p1 = (lane < NC - 64) && (s1 > SCORE_T);
        u64 m0 = __ballot(p0);
        u64 m1 = __ballot(p1);
        int c0  = __popcll(m0);
        int cnt = c0 + __popcll(m1);

        int base = 0;
        if (lane == 0 && cnt) base = atomicAdd(&s_cnt, cnt);
        base = __shfl(base, 0);
        if (p0) {
            int pos  = base + __popcll(m0 & lm);
            int flat = n * NCM1 + (lane - 1);
            stage[pos] = ((u64)__float_as_uint(s0) << 32) | (u32)(~(u32)flat);
        }
        if (p1) {
            int pos  = base + c0 + __popcll(m1 & lm);
            int flat = n * NCM1 + (64 + lane - 1);
            stage[pos] = ((u64)__float_as_uint(s1) << 32) | (u32)(~(u32)flat);
        }
    }
    __syncthreads();

    if (threadIdx.x == 0) s_base = atomicAdd(&gcount[b], s_cnt);
    __syncthreads();
    int m = s_cnt, base = s_base;
    u64* kb = dense + (long)b * CAP_D + base;
    for (int i = threadIdx.x; i < m; i += 256) kb[i] = stage[i];
}

// ---------------- Kernel 2: dual-rank radix select over dense (round-8/10/12 verified) ----------------
__global__ __launch_bounds__(1024) void k_select(const u64* __restrict__ dense,
                                                 const int* __restrict__ nsel,
                                                 u64* __restrict__ Tsel,
                                                 u64* __restrict__ Tsel2) {
    __shared__ int hist[2048];
    __shared__ int s_sel, s_gt;
    int blk = blockIdx.x;
    int b   = blk & (BDIM - 1);
    int rank = (blk < BDIM) ? MSEL : NSORT;
    u64* dst = (blk < BDIM) ? (Tsel + b) : (Tsel2 + b);
    int tid = threadIdx.x;
    int n = nsel[b]; if (n > CAP_D) n = CAP_D;
    if (n <= rank) { if (tid == 0) *dst = 0ull; return; }

    const u64* kb = dense + (long)b * CAP_D;
    u64 prefix = 0, mask = 0;
    const int shifts[6] = {53, 42, 31, 20, 10, 0};
    const int bitsv [6] = {11, 11, 11, 11, 10, 10};

    for (int pass = 0; pass < 6; ++pass) {
        int shift = shifts[pass];
        int nb = 1 << bitsv[pass];
        if (tid < nb) hist[tid] = 0;
        if (tid + 1024 < nb) hist[tid + 1024] = 0;
        __syncthreads();
        for (int i = tid; i < n; i += 1024) {
            u64 k = kb[i];
            if ((k & mask) == prefix)
                atomicAdd(&hist[(int)((k >> shift) & (u64)(nb - 1))], 1);
        }
        __syncthreads();
        for (int d = 1; d < nb; d <<= 1) {
            int v0 = 0, v1 = 0;
            if (tid < nb && tid + d < nb) v0 = hist[tid + d];
            if (tid + 1024 < nb && tid + 1024 + d < nb) v1 = hist[tid + 1024 + d];
            __syncthreads();
            if (tid < nb) hist[tid] += v0;
            if (tid + 1024 < nb) hist[tid + 1024] += v1;
            __syncthreads();
        }
        for (int j = tid; j < nb; j += 1024) {
            int c  = hist[j];
            int cn = (j + 1 < nb) ? hist[j + 1] : 0;
            if (c >= rank && cn < rank) { s_sel = j; s_gt = cn; }
        }
        __syncthreads();
        prefix |= ((u64)s_sel) << shift;
        mask   |= ((u64)(nb - 1)) << shift;
        rank   -= s_gt;
        __syncthreads();
    }
    if (tid == 0) *dst = prefix;
}

// ---------------- Kernel 3: gather + register bitonic sort -> sorted top-1024 keys to ws ----------------
__global__ __launch_bounds__(TN) void k_prep(const u64* __restrict__ dense,
                                             const int* __restrict__ nsel,
                                             const u64* __restrict__ Tsel2,
                                             u64* __restrict__ sk_ws,
                                             int* __restrict__ mb_ws) {
    __shared__ u64 skey[NSORT];
    __shared__ int s_cnt;

    int b = blockIdx.x, tid = threadIdx.x;
    int lane = tid & 63;
    int n = nsel[b]; if (n > CAP_D) n = CAP_D;
    u64 T2 = Tsel2[b];
    const u64* kb = dense + (long)b * CAP_D;
    u64 lm = (1ull << lane) - 1ull;
    int npad = (n + TN - 1) & ~(TN - 1);

    skey[tid] = 0ull;
    if (tid == 0) s_cnt = 0;
    __syncthreads();
    // wave-aggregated flat gather (round-8/12/13 verified)
    for (int i0 = tid; i0 < npad; i0 += TN) {
        bool inb = (i0 < n);
        u64 k = inb ? kb[i0] : 0ull;
        bool pred = inb && (k >= T2);
        u64 mb_ = __ballot(pred);
        int cnt = __popcll(mb_);
        int bp = 0;
        if (lane == 0 && cnt) bp = atomicAdd(&s_cnt, cnt);
        bp = __shfl(bp, 0);
        if (pred) {
            int pos = bp + __popcll(mb_ & lm);
            if (pos < NSORT) skey[pos] = k;
        }
    }
    __syncthreads();
    int mb = s_cnt; if (mb > NSORT) mb = NSORT;

    // register bitonic, 1 element/thread; shfl for j<64, LDS for j>=64 (round-8..13 verified)
    u64 r = skey[tid];
    for (int kk = 2; kk <= NSORT; kk <<= 1) {
        for (int j = kk >> 1; j; j >>= 1) {
            u64 p;
            if (j >= 64) {
                skey[tid] = r;
                __syncthreads();
                p = skey[tid ^ j];
                __syncthreads();
            } else {
                p = __shfl_xor(r, j);
            }
            bool lower = (tid & j) == 0;
            bool desc  = ((tid & kk) == 0);
            u64 mx = (r > p) ? r : p;
            u64 mn = (r > p) ? p : r;
            r = (lower == desc) ? mx : mn;
        }
    }
    sk_ws[b * NSORT + tid] = r;
    if (tid == 0) mb_ws[b] = mb;
}

// ---------------- Kernel 4: parallel decode of sorted keys (64 blocks) ----------------
__global__ __launch_bounds__(256) void k_decode(const u64* __restrict__ sk_ws,
                                                const int* __restrict__ mb_ws,
                                                const float* __restrict__ boxreg,
                                                const float* __restrict__ props,
                                                float4* __restrict__ box_ws,
                                                float2* __restrict__ pack_ws) {
    int b = blockIdx.y;
    int i = blockIdx.x * 256 + threadIdx.x;
    if (i >= mb_ws[b]) return;
    u64 k = sk_ws[b * NSORT + i];
    float4 bx; float2 pk;
    DECODE_BODY(k, b, bx, pk);
    box_ws[b * NSORT + i] = bx;
    pack_ws[b * NSORT + i] = pk;
}

// ---------------- Kernel 5: chunk-parallel walk (+ exact batch-1 fallback) ----------------
__global__ __launch_bounds__(TN) void k_walk(const u64* __restrict__ dense,
                                             const int* __restrict__ nsel,
                                             const u64* __restrict__ Tsel,
                                             const u64* __restrict__ Tsel2,
                                             const u64* __restrict__ sk_ws,
                                             const int* __restrict__ mb_ws,
                                             const float4* __restrict__ box_ws,
                                             const float2* __restrict__ pack_ws,
                                             const float* __restrict__ boxreg,
                                             const float* __restrict__ props,
                                             float* __restrict__ out) {
    __shared__ u64 skey[MSEL];          // fallback only
    __shared__ float4 sbox[MSEL];
    __shared__ float2 spack[MSEL];
    __shared__ float4 cboxS[64];
    __shared__ float2 cpackS[64];
    __shared__ float aX1[AMAX], aY1[AMAX], aX2[AMAX], aY2[AMAX], aArea[AMAX], aLab[AMAX];
    __shared__ u64 aKey[AMAX];
    __shared__ int s_cnt, s_nacc;

    int b = blockIdx.x, tid = threadIdx.x;
    int lane = tid & 63, wid = tid >> 6;
    int n = nsel[b]; if (n > CAP_D) n = CAP_D;
    u64 T  = Tsel[b];
    u64 T2 = Tsel2[b];
    const u64* kb = dense + (long)b * CAP_D;
    u64 lm = (1ull << lane) - 1ull;
    int mb0 = mb_ws[b];

    int nacc = 0;

    // ---- batch-0 walk: wave 0, reading precomputed sorted keys/boxes from ws ----
    if (wid == 0) {
        for (int c0 = 0; c0 < mb0 && nacc < KOUT; c0 += 64) {
            int i = c0 + lane;
            bool valid = (i < mb0);
            float4 Bv = valid ? box_ws[b * NSORT + i] : make_float4(0.f, 0.f, 0.f, 0.f);
            float2 pk = valid ? pack_ws[b * NSORT + i] : make_float2(0.f, -1.f);
            u64    ck = valid ? sk_ws[b * NSORT + i] : 0ull;
            float areaB = pk.x, labf = pk.y;
            float off = __fmul_rn(labf, OFFSETF);
            cboxS[lane] = Bv;
            cpackS[lane] = pk;
            __builtin_amdgcn_wave_barrier();

            bool conf = false;
            for (int a = 0; a < nacc; ++a) {
                if (aLab[a] == labf) {
                    float op1x = __fadd_rn(fminf(aX2[a], Bv.z), off);
                    float op2x = __fadd_rn(fmaxf(aX1[a], Bv.x), off);
                    float iw = fmaxf(op1x - op2x, 0.0f);
                    float op1y = __fadd_rn(fminf(aY2[a], Bv.w), off);
                    float op2y = __fadd_rn(fmaxf(aY1[a], Bv.y), off);
                    float ih = fmaxf(op1y - op2y, 0.0f);
                    float inter = iw * ih;
                    float denom = areaB + aArea[a] - inter + 1e-9f;
                    if (inter / denom > NMS_T) conf = true;
                }
            }
            u64 validmask = __ballot(valid);
            u64 deadmask  = __ballot(conf);

            u64 rowm = 0;
            for (int t = 0; t < 64; ++t) {
                if (t != lane) {
                    float2 tp = cpackS[t];
                    if (tp.y == labf) {
                        float4 Tv = cboxS[t];
                        float op1x = __fadd_rn(fminf(Tv.z, Bv.z), off);
                        float op2x = __fadd_rn(fmaxf(Tv.x, Bv.x), off);
                        float iw = fmaxf(op1x - op2x, 0.0f);
                        float op1y = __fadd_rn(fminf(Tv.w, Bv.w), off);
                        float op2y = __fadd_rn(fmaxf(Tv.y, Bv.y), off);
                        float ih = fmaxf(op1y - op2y, 0.0f);
                        float inter = iw * ih;
                        float denom = areaB + tp.x - inter + 1e-9f;
                        if (inter / denom > NMS_T) rowm |= (1ull << t);
                    }
                }
            }

            u64 alive = validmask & ~deadmask;
            u64 acc = 0;
            int room = KOUT - nacc;
            while (alive && room) {
                int j = __builtin_ctzll(alive);
                acc |= (1ull << j);
                --room;
                u64 rj = __shfl(rowm, j);
                alive &= ~rj;
                alive &= ~(1ull << j);
            }

            if (acc & (1ull << lane)) {
                int idx = nacc + __popcll(acc & lm);
                aX1[idx] = Bv.x; aY1[idx] = Bv.y; aX2[idx] = Bv.z; aY2[idx] = Bv.w;
                aArea[idx] = areaB; aLab[idx] = labf;
                aKey[idx] = ck;
            }
            __builtin_amdgcn_wave_barrier();
            nacc += __popcll(acc);
        }
        if (lane == 0) s_nacc = nacc;
    }
    __syncthreads();

    // ---- batch-1 exact fallback (round-13 verified path; rare) ----
    if (s_nacc < KOUT && T2 != 0ull) {
        int npad = (n + TN - 1) & ~(TN - 1);
        for (int i = tid; i < MSEL; i += TN) skey[i] = 0ull;
        if (tid == 0) s_cnt = 0;
        __syncthreads();
        for (int i0 = tid; i0 < npad; i0 += TN) {
            bool inb = (i0 < n);
            u64 k = inb ? kb[i0] : 0ull;
            bool pred = inb && (k >= T && k < T2);
            u64 mb_ = __ballot(pred);
            int cnt = __popcll(mb_);
            int bp = 0;
            if (lane == 0 && cnt) bp = atomicAdd(&s_cnt, cnt);
            bp = __shfl(bp, 0);
            if (pred) {
                int pos = bp + __popcll(mb_ & lm);
                if (pos < MSEL) skey[pos] = k;
            }
        }
        __syncthreads();
        int mb2 = s_cnt; if (mb2 > MSEL) mb2 = MSEL;

        for (int kk = 2; kk <= MSEL; kk <<= 1) {
            for (int j = kk >> 1; j > 0; j >>= 1) {
                for (int t = tid; t < MSEL; t += TN) {
                    int l = t ^ j;
                    if (l > t) {
                        u64 a = skey[t], c = skey[l];
                        bool up = ((t & kk) == 0);
                        bool sw = up ? (a < c) : (a > c);
                        if (sw) { skey[t] = c; skey[l] = a; }
                    }
                }
                __syncthreads();
            }
        }

        for (int i = tid; i < mb2; i += TN) {
            u64 k = skey[i];
            float4 bx; float2 pk;
            DECODE_BODY(k, b, bx, pk);
            sbox[i] = bx;
            spack[i] = pk;
        }
        __syncthreads();

        if (wid == 0) {
            for (int c0 = 0; c0 < mb2 && nacc < KOUT; c0 += 64) {
                int i = c0 + lane;
                bool valid = (i < mb2);
                float4 Bv = valid ? sbox[i] : make_float4(0.f, 0.f, 0.f, 0.f);
                float2 pk = valid ? spack[i] : make_float2(0.f, -1.f);
                float areaB = pk.x, labf = pk.y;
                float off = __fmul_rn(labf, OFFSETF);
                cboxS[lane] = Bv;
                cpackS[lane] = pk;
                __builtin_amdgcn_wave_barrier();

                bool conf = false;
                for (int a = 0; a < nacc; ++a) {
                    if (aLab[a] == labf) {
                        float op1x = __fadd_rn(fminf(aX2[a], Bv.z), off);
                        float op2x = __fadd_rn(fmaxf(aX1[a], Bv.x), off);
                        float iw = fmaxf(op1x - op2x, 0.0f);
                        float op1y = __fadd_rn(fminf(aY2[a], Bv.w), off);
                        float op2y = __fadd_rn(fmaxf(aY1[a], Bv.y), off);
                        float ih = fmaxf(op1y - op2y, 0.0f);
                        float inter = iw * ih;
                        float denom = areaB + aArea[a] - inter + 1e-9f;
                        if (inter / denom > NMS_T) conf = true;
                    }
                }
                u64 validmask = __ballot(valid);
                u64 deadmask  = __ballot(conf);

                u64 rowm = 0;
                for (int t = 0; t < 64; ++t) {
                    if (t != lane) {
                        float2 tp = cpackS[t];
                        if (tp.y == labf) {
                            float4 Tv = cboxS[t];
                            float op1x = __fadd_rn(fminf(Tv.z, Bv.z), off);
                            float op2x = __fadd_rn(fmaxf(Tv.x, Bv.x), off);
                            float iw = fmaxf(op1x - op2x, 0.0f);
                            float op1y = __fadd_rn(fminf(Tv.w, Bv.w), off);
                            float op2y = __fadd_rn(fmaxf(Tv.y, Bv.y), off);
                            float ih = fmaxf(op1y - op2y, 0.0f);
                            float inter = iw * ih;
                            float denom = areaB + tp.x - inter + 1e-9f;
                            if (inter / denom > NMS_T) rowm |= (1ull << t);
                        }
                    }
                }

                u64 alive = validmask & ~deadmask;
                u64 acc = 0;
                int room = KOUT - nacc;
                while (alive && room) {
                    int j = __builtin_ctzll(alive);
                    acc |= (1ull << j);
                    --room;
                    u64 rj = __shfl(rowm, j);
                    alive &= ~rj;
                    alive &= ~(1ull << j);
                }

                if (acc & (1ull << lane)) {
                    int idx = nacc + __popcll(acc & lm);
                    aX1[idx] = Bv.x; aY1[idx] = Bv.y; aX2[idx] = Bv.z; aY2[idx] = Bv.w;
                    aArea[idx] = areaB; aLab[idx] = labf;
                    aKey[idx] = skey[i];
                }
                __builtin_amdgcn_wave_barrier();
                nacc += __popcll(acc);
            }
            if (lane == 0) s_nacc = nacc;
        }
        __syncthreads();
    }

    // ---- emit outputs in acceptance order ----
    int na = s_nacc; if (na > KOUT) na = KOUT;
    for (int a = tid; a < KOUT; a += TN) {
        float* ob = out + ((long)b * KOUT + a) * 4;
        if (a < na) {
            ob[0] = aX1[a]; ob[1] = aY1[a]; ob[2] = aX2[a]; ob[3] = aY2[a];
            out[BDIM * KOUT * 4 + b * KOUT + a] = __uint_as_float((u32)(aKey[a] >> 32));
            out[BDIM * KOUT * 5 + b * KOUT + a] = aLab[a];
            out[BDIM * KOUT * 6 + b * KOUT + a] = 1.0f;
        } else {
            ob[0] = 0.0f; ob[1] = 0.0f; ob[2] = 0.0f; ob[3] = 0.0f;
            out[BDIM * KOUT * 4 + b * KOUT + a] = 0.0f;
            out[BDIM * KOUT * 5 + b * KOUT + a] = -1.0f;
            out[BDIM * KOUT * 6 + b * KOUT + a] = 0.0f;
        }
    }
}

extern "C" void kernel_launch(void* const* d_in, const int* in_sizes, int n_in,
                              void* d_out, int out_size, void* d_ws, size_t ws_size,
                              hipStream_t stream) {
    const float* logits = (const float*)d_in[0];
    const float* boxreg = (const float*)d_in[1];
    const float* props  = (const float*)d_in[2];
    float* out = (float*)d_out;

    char* ws = (char*)d_ws;
    int* gcount = (int*)(ws + 0);                 // 64 B
    u64* Tsel   = (u64*)(ws + 256);               // 128 B
    u64* Tsel2  = (u64*)(ws + 512);               // 128 B
    int* mb_ws  = (int*)(ws + 768);               // 64 B
    u64* sk_ws  = (u64*)(ws + 1024);              // 16*1024*8  = 128 KB
    float2* pack_ws = (float2*)(ws + 132096);     // 16*1024*8  = 128 KB
    float4* box_ws  = (float4*)(ws + 263168);     // 16*1024*16 = 256 KB
    u64* dense  = (u64*)(ws + 525312);            // 16*77824*8 = 9.96 MB

    k_zero<<<1, 64, 0, stream>>>(gcount);
    k_soft<<<(BDIM * NP) / RPB, 256, 0, stream>>>(logits, dense, gcount);
    k_select<<<2 * BDIM, 1024, 0, stream>>>(dense, gcount, Tsel, Tsel2);
    k_prep<<<BDIM, TN, 0, stream>>>(dense, gcount, Tsel2, sk_ws, mb_ws);
    k_decode<<<dim3(4, BDIM), 256, 0, stream>>>(sk_ws, mb_ws, boxreg, props, box_ws, pack_ws);
    k_walk<<<BDIM, TN, 0, stream>>>(dense, gcount, Tsel, Tsel2, sk_ws, mb_ws,
                                    box_ws, pack_ws, boxreg, props, out);
}

// Round 15
// 106.154 us; speedup vs baseline: 1.2084x; 1.2084x over previous
//
#include <hip/hip_runtime.h>

typedef unsigned long long u64;
typedef unsigned int u32;

#define BDIM 16
#define NP   4096
#define NC   91
#define NCM1 90
#define MSEL 4096       // top-M per image (reference M)
#define NSORT 1024      // batch-0 sorted prefix size
#define KOUT 100
#define RSLOT 19        // max candidates per row (scores sum to 1, >0.05 => <=19)
#define CAP_D (NP * RSLOT)   // 77824: provable per-image max -> no overflow possible
#define SCORE_T 0.05f
#define NMS_T   0.5f
#define OFFSETF 10000.0f
#define DW_CLAMP_F 4.135166556742356f
#define WF 1333.0f
#define HF 800.0f

#define TN 1024
#define RPB 64            // rows per k_soft block (64 blocks per image)

// decode expressions (round-6..14 verified, byte-identical)
#define DECODE_BODY(kvar, bvar, BOXDST, PACKDST)                                   \
    {                                                                              \
        int flat = (int)(~(u32)(kvar));                                            \
        int nidx = flat / NCM1;                                                    \
        int c    = flat - nidx * NCM1 + 1;                                         \
        const float* pr = props + ((long)(bvar) * NP + nidx) * 4;                  \
        float x1 = pr[0], y1 = pr[1], x2 = pr[2], y2 = pr[3];                      \
        float w = x2 - x1, h = y2 - y1;                                            \
        float cx = x1 + 0.5f * w, cy = y1 + 0.5f * h;                              \
        const float* rr = boxreg + (((long)(bvar) * NP + nidx) * NC + c) * 4;      \
        float dx = rr[0] / 10.0f, dy = rr[1] / 10.0f;                              \
        float dw = fminf(rr[2] / 5.0f, DW_CLAMP_F);                                \
        float dh = fminf(rr[3] / 5.0f, DW_CLAMP_F);                                \
        float pcx = __fadd_rn(__fmul_rn(dx, w), cx);                               \
        float pcy = __fadd_rn(__fmul_rn(dy, h), cy);                               \
        float pw  = __fmul_rn(expf(dw), w);                                        \
        float ph2 = __fmul_rn(expf(dh), h);                                        \
        float bx1 = fminf(fmaxf(pcx - 0.5f * pw, 0.0f), WF);                       \
        float by1 = fminf(fmaxf(pcy - 0.5f * ph2, 0.0f), HF);                      \
        float bx2 = fminf(fmaxf(pcx + 0.5f * pw, 0.0f), WF);                       \
        float by2 = fminf(fmaxf(pcy + 0.5f * ph2, 0.0f), HF);                      \
        BOXDST = make_float4(bx1, by1, bx2, by2);                                  \
        float offB = (float)c * OFFSETF;                                           \
        float ox1 = bx1 + offB, oy1 = by1 + offB;                                  \
        float ox2 = bx2 + offB, oy2 = by2 + offB;                                  \
        PACKDST = make_float2((ox2 - ox1) * (oy2 - oy1), (float)c);                \
    }

// ---------------- Kernel 0: zero the 16 per-image counters ----------------
__global__ __launch_bounds__(64) void k_zero(int* __restrict__ gcount) {
    if (threadIdx.x < BDIM) gcount[threadIdx.x] = 0;
}

// ---------------- Kernel 1: softmax -> dense candidates (round-10/12 verified) ----------------
__global__ __launch_bounds__(256) void k_soft(const float* __restrict__ logits,
                                              u64* __restrict__ dense,
                                              int* __restrict__ gcount) {
    __shared__ u64 stage[RPB * RSLOT];
    __shared__ int s_cnt, s_base;

    int blk  = blockIdx.x;
    int b    = blk >> 6;
    int lane = threadIdx.x & 63;
    int wid  = threadIdx.x >> 6;

    if (threadIdx.x == 0) s_cnt = 0;
    __syncthreads();

    u64 lm = (1ull << lane) - 1ull;
    for (int it = 0; it < RPB / 4; ++it) {
        int row = blk * RPB + it * 4 + wid;
        const float* lg = logits + (long)row * NC;

        float v0 = lg[lane];
        float v1 = (lane < NC - 64) ? lg[64 + lane] : -3.0e38f;
        float mx = fmaxf(v0, v1);
#pragma unroll
        for (int s = 32; s; s >>= 1) mx = fmaxf(mx, __shfl_xor(mx, s));
        float e0 = expf(v0 - mx);
        float e1 = (lane < NC - 64) ? expf(v1 - mx) : 0.0f;
        float sum = e0 + e1;
#pragma unroll
        for (int s = 32; s; s >>= 1) sum += __shfl_xor(sum, s);

        float s0 = e0 / sum;
        float s1 = e1 / sum;

        int n = row & (NP - 1);
        bool p0 = (lane >= 1) && (s0 > SCORE_T);
        bool p1 = (lane < NC - 64) && (s1 > SCORE_T);
        u64 m0 = __ballot(p0);
        u64 m1 = __ballot(p1);
        int c0  = __popcll(m0);
        int cnt = c0 + __popcll(m1);

        int base = 0;
        if (lane == 0 && cnt) base = atomicAdd(&s_cnt, cnt);
        base = __shfl(base, 0);
        if (p0) {
            int pos  = base + __popcll(m0 & lm);
            int flat = n * NCM1 + (lane - 1);
            stage[pos] = ((u64)__float_as_uint(s0) << 32) | (u32)(~(u32)flat);
        }
        if (p1) {
            int pos  = base + c0 + __popcll(m1 & lm);
            int flat = n * NCM1 + (64 + lane - 1);
            stage[pos] = ((u64)__float_as_uint(s1) << 32) | (u32)(~(u32)flat);
        }
    }
    __syncthreads();

    if (threadIdx.x == 0) s_base = atomicAdd(&gcount[b], s_cnt);
    __syncthreads();
    int m = s_cnt, base = s_base;
    u64* kb = dense + (long)b * CAP_D + base;
    for (int i = threadIdx.x; i < m; i += 256) kb[i] = stage[i];
}

// ---------------- radix rank-select device function (round-8/10/12 verified body) ----------------
__device__ __forceinline__ u64 radix_rank(const u64* __restrict__ kb, int n, int rank,
                                          int* hist, int* p_sel, int* p_gt, int tid) {
    u64 prefix = 0, mask = 0;
    const int shifts[6] = {53, 42, 31, 20, 10, 0};
    const int bitsv [6] = {11, 11, 11, 11, 10, 10};

    for (int pass = 0; pass < 6; ++pass) {
        int shift = shifts[pass];
        int nb = 1 << bitsv[pass];
        if (tid < nb) hist[tid] = 0;
        if (tid + 1024 < nb) hist[tid + 1024] = 0;
        __syncthreads();
        for (int i = tid; i < n; i += 1024) {
            u64 k = kb[i];
            if ((k & mask) == prefix)
                atomicAdd(&hist[(int)((k >> shift) & (u64)(nb - 1))], 1);
        }
        __syncthreads();
        for (int d = 1; d < nb; d <<= 1) {
            int v0 = 0, v1 = 0;
            if (tid < nb && tid + d < nb) v0 = hist[tid + d];
            if (tid + 1024 < nb && tid + 1024 + d < nb) v1 = hist[tid + 1024 + d];
            __syncthreads();
            if (tid < nb) hist[tid] += v0;
            if (tid + 1024 < nb) hist[tid + 1024] += v1;
            __syncthreads();
        }
        for (int j = tid; j < nb; j += 1024) {
            int c  = hist[j];
            int cn = (j + 1 < nb) ? hist[j + 1] : 0;
            if (c >= rank && cn < rank) { *p_sel = j; *p_gt = cn; }
        }
        __syncthreads();
        prefix |= ((u64)(*p_sel)) << shift;
        mask   |= ((u64)(nb - 1)) << shift;
        rank   -= *p_gt;
        __syncthreads();
    }
    return prefix;   // uniform across block
}

// ---------------- Kernel 2: fused select + gather + sort + decode + walk NMS ----------------
__global__ __launch_bounds__(TN) void k_post(const u64* __restrict__ dense,
                                             const int* __restrict__ gcount,
                                             const float* __restrict__ boxreg,
                                             const float* __restrict__ props,
                                             float* __restrict__ out) {
    __shared__ __align__(16) char ldsbuf[131072];   // aliased phases, 128 KB
    __shared__ int s_cnt, s_nacc, s_sel, s_gt;

    // batch-0 layout
    float4* sbox  = (float4*)ldsbuf;                // 16 KB (1024)
    float2* spack = (float2*)(ldsbuf + 16384);      //  8 KB
    u64*    skey  = (u64*)(ldsbuf + 24576);         //  8 KB
    int*    hist  = (int*)(ldsbuf + 32768);         //  8 KB

    int b = blockIdx.x, tid = threadIdx.x;
    int lane = tid & 63, wid = tid >> 6;
    int n = gcount[b]; if (n > CAP_D) n = CAP_D;
    const u64* kb = dense + (long)b * CAP_D;
    u64 lm = (1ull << lane) - 1ull;
    int npad = (n + TN - 1) & ~(TN - 1);

    // ---- T2 = NSORT-th largest key (0 => take all) ----
    u64 T2 = 0ull;
    if (n > NSORT) T2 = radix_rank(kb, n, NSORT, hist, &s_sel, &s_gt, tid);

    // ---- gather batch-0: keys >= T2 (round-8/12 verified pattern) ----
    skey[tid] = 0ull;
    if (tid == 0) s_cnt = 0;
    __syncthreads();
    for (int i0 = tid; i0 < npad; i0 += TN) {
        bool inb = (i0 < n);
        u64 k = inb ? kb[i0] : 0ull;
        bool pred = inb && (k >= T2);
        u64 mb_ = __ballot(pred);
        int cnt = __popcll(mb_);
        int bp = 0;
        if (lane == 0 && cnt) bp = atomicAdd(&s_cnt, cnt);
        bp = __shfl(bp, 0);
        if (pred) {
            int pos = bp + __popcll(mb_ & lm);
            if (pos < NSORT) skey[pos] = k;
        }
    }
    __syncthreads();
    int mb = s_cnt; if (mb > NSORT) mb = NSORT;

    // ---- register bitonic sort desc over 1024 (round-8/12 verified) ----
    {
        u64 r = skey[tid];
        for (int kk = 2; kk <= NSORT; kk <<= 1) {
            for (int j = kk >> 1; j; j >>= 1) {
                u64 p;
                if (j >= 64) {
                    skey[tid] = r;
                    __syncthreads();
                    p = skey[tid ^ j];
                    __syncthreads();
                } else {
                    p = __shfl_xor(r, j);
                }
                bool lower = (tid & j) == 0;
                bool desc  = ((tid & kk) == 0);
                u64 mx = (r > p) ? r : p;
                u64 mn = (r > p) ? p : r;
                r = (lower == desc) ? mx : mn;
            }
        }
        skey[tid] = r;
        __syncthreads();
    }

    // ---- decode sorted candidates (all 16 waves, scattered loads in parallel) ----
    for (int i = tid; i < mb; i += TN) {
        u64 k = skey[i];
        float4 bx; float2 pk;
        DECODE_BODY(k, b, bx, pk);
        sbox[i] = bx;
        spack[i] = pk;
    }
    __syncthreads();

    // accepted list: wave-0 lane registers, 2 slots/lane (round-8/12 verified)
    float ax1_0 = 0, ay1_0 = 0, ax2_0 = 0, ay2_0 = 0, aar_0 = 0;
    float ax1_1 = 0, ay1_1 = 0, ax2_1 = 0, ay2_1 = 0, aar_1 = 0;
    int alb_0 = -1, alb_1 = -1;
    u64 aky_0 = 0, aky_1 = 0;
    int nacc = 0;

    // ---- serial walk in sorted order (round-8/12 verified text) ----
    if (wid == 0) {
        float4 Bv = sbox[0];
        float2 pk = spack[0];
        u64    ck = skey[0];
        for (int i = 0; i < mb && nacc < KOUT; ++i) {
            int ip = (i + 1 < mb) ? i + 1 : i;
            float4 nBv = sbox[ip];
            float2 npk = spack[ip];
            u64    nck = skey[ip];

            float areaB = pk.x;
            float labf  = pk.y;
            float off   = __fmul_rn(labf, OFFSETF);
            bool conf = false;
            if (lane < nacc && (float)alb_0 == labf) {
                float op1x = __fadd_rn(fminf(ax2_0, Bv.z), off);
                float op2x = __fadd_rn(fmaxf(ax1_0, Bv.x), off);
                float iw = fmaxf(op1x - op2x, 0.0f);
                float op1y = __fadd_rn(fminf(ay2_0, Bv.w), off);
                float op2y = __fadd_rn(fmaxf(ay1_0, Bv.y), off);
                float ih = fmaxf(op1y - op2y, 0.0f);
                float inter = iw * ih;
                float denom = areaB + aar_0 - inter + 1e-9f;
                if (inter / denom > NMS_T) conf = true;
            }
            if (64 + lane < nacc && (float)alb_1 == labf) {
                float op1x = __fadd_rn(fminf(ax2_1, Bv.z), off);
                float op2x = __fadd_rn(fmaxf(ax1_1, Bv.x), off);
                float iw = fmaxf(op1x - op2x, 0.0f);
                float op1y = __fadd_rn(fminf(ay2_1, Bv.w), off);
                float op2y = __fadd_rn(fmaxf(ay1_1, Bv.y), off);
                float ih = fmaxf(op1y - op2y, 0.0f);
                float inter = iw * ih;
                float denom = areaB + aar_1 - inter + 1e-9f;
                if (inter / denom > NMS_T) conf = true;
            }
            if (__ballot(conf) == 0ull) {
                if (nacc < 64) {
                    if (lane == nacc) {
                        ax1_0 = Bv.x; ay1_0 = Bv.y; ax2_0 = Bv.z; ay2_0 = Bv.w;
                        aar_0 = areaB; alb_0 = (int)labf; aky_0 = ck;
                    }
                } else {
                    if (lane == nacc - 64) {
                        ax1_1 = Bv.x; ay1_1 = Bv.y; ax2_1 = Bv.z; ay2_1 = Bv.w;
                        aar_1 = areaB; alb_1 = (int)labf; aky_1 = ck;
                    }
                }
                ++nacc;
            }
            Bv = nBv; pk = npk; ck = nck;
        }
        if (lane == 0) s_nacc = nacc;
    }
    __syncthreads();

    // ---- exact fallback: ranks 1025..4096 (rare; lazy T; aliased LDS) ----
    if (s_nacc < KOUT && T2 != 0ull) {
        u64 T = 0ull;
        if (n > MSEL) T = radix_rank(kb, n, MSEL, hist, &s_sel, &s_gt, tid);

        u64*    fkey  = (u64*)ldsbuf;               // 32 KB (4096)
        float4* fbox  = (float4*)(ldsbuf + 32768);  // 64 KB (overwrites hist after radix done)
        float2* fpack = (float2*)(ldsbuf + 98304);  // 32 KB

        for (int i = tid; i < MSEL; i += TN) fkey[i] = 0ull;
        if (tid == 0) s_cnt = 0;
        __syncthreads();
        for (int i0 = tid; i0 < npad; i0 += TN) {
            bool inb = (i0 < n);
            u64 k = inb ? kb[i0] : 0ull;
            bool pred = inb && (k >= T && k < T2);
            u64 mb_ = __ballot(pred);
            int cnt = __popcll(mb_);
            int bp = 0;
            if (lane == 0 && cnt) bp = atomicAdd(&s_cnt, cnt);
            bp = __shfl(bp, 0);
            if (pred) {
                int pos = bp + __popcll(mb_ & lm);
                if (pos < MSEL) fkey[pos] = k;
            }
        }
        __syncthreads();
        int mb2 = s_cnt; if (mb2 > MSEL) mb2 = MSEL;

        // LDS bitonic over MSEL (round-7/12 verified)
        for (int kk = 2; kk <= MSEL; kk <<= 1) {
            for (int j = kk >> 1; j > 0; j >>= 1) {
                for (int t = tid; t < MSEL; t += TN) {
                    int l = t ^ j;
                    if (l > t) {
                        u64 a = fkey[t], c = fkey[l];
                        bool up = ((t & kk) == 0);
                        bool sw = up ? (a < c) : (a > c);
                        if (sw) { fkey[t] = c; fkey[l] = a; }
                    }
                }
                __syncthreads();
            }
        }

        for (int i = tid; i < mb2; i += TN) {
            u64 k = fkey[i];
            float4 bx; float2 pk;
            DECODE_BODY(k, b, bx, pk);
            fbox[i] = bx;
            fpack[i] = pk;
        }
        __syncthreads();

        if (wid == 0) {
            float4 Bv = fbox[0];
            float2 pk = fpack[0];
            u64    ck = fkey[0];
            for (int i = 0; i < mb2 && nacc < KOUT; ++i) {
                int ip = (i + 1 < mb2) ? i + 1 : i;
                float4 nBv = fbox[ip];
                float2 npk = fpack[ip];
                u64    nck = fkey[ip];

                float areaB = pk.x;
                float labf  = pk.y;
                float off   = __fmul_rn(labf, OFFSETF);
                bool conf = false;
                if (lane < nacc && (float)alb_0 == labf) {
                    float op1x = __fadd_rn(fminf(ax2_0, Bv.z), off);
                    float op2x = __fadd_rn(fmaxf(ax1_0, Bv.x), off);
                    float iw = fmaxf(op1x - op2x, 0.0f);
                    float op1y = __fadd_rn(fminf(ay2_0, Bv.w), off);
                    float op2y = __fadd_rn(fmaxf(ay1_0, Bv.y), off);
                    float ih = fmaxf(op1y - op2y, 0.0f);
                    float inter = iw * ih;
                    float denom = areaB + aar_0 - inter + 1e-9f;
                    if (inter / denom > NMS_T) conf = true;
                }
                if (64 + lane < nacc && (float)alb_1 == labf) {
                    float op1x = __fadd_rn(fminf(ax2_1, Bv.z), off);
                    float op2x = __fadd_rn(fmaxf(ax1_1, Bv.x), off);
                    float iw = fmaxf(op1x - op2x, 0.0f);
                    float op1y = __fadd_rn(fminf(ay2_1, Bv.w), off);
                    float op2y = __fadd_rn(fmaxf(ay1_1, Bv.y), off);
                    float ih = fmaxf(op1y - op2y, 0.0f);
                    float inter = iw * ih;
                    float denom = areaB + aar_1 - inter + 1e-9f;
                    if (inter / denom > NMS_T) conf = true;
                }
                if (__ballot(conf) == 0ull) {
                    if (nacc < 64) {
                        if (lane == nacc) {
                            ax1_0 = Bv.x; ay1_0 = Bv.y; ax2_0 = Bv.z; ay2_0 = Bv.w;
                            aar_0 = areaB; alb_0 = (int)labf; aky_0 = ck;
                        }
                    } else {
                        if (lane == nacc - 64) {
                            ax1_1 = Bv.x; ay1_1 = Bv.y; ax2_1 = Bv.z; ay2_1 = Bv.w;
                            aar_1 = areaB; alb_1 = (int)labf; aky_1 = ck;
                        }
                    }
                    ++nacc;
                }
                Bv = nBv; pk = npk; ck = nck;
            }
            if (lane == 0) s_nacc = nacc;
        }
        __syncthreads();
    }

    // ---- emit outputs in acceptance order (round-8/12 verified) ----
    int na = s_nacc; if (na > KOUT) na = KOUT;
    if (wid == 0) {
        if (lane < na) {
            int a = lane;
            float* ob = out + ((long)b * KOUT + a) * 4;
            ob[0] = ax1_0; ob[1] = ay1_0; ob[2] = ax2_0; ob[3] = ay2_0;
            out[BDIM * KOUT * 4 + b * KOUT + a] = __uint_as_float((u32)(aky_0 >> 32));
            out[BDIM * KOUT * 5 + b * KOUT + a] = (float)alb_0;
            out[BDIM * KOUT * 6 + b * KOUT + a] = 1.0f;
        }
        if (64 + lane < na) {
            int a = 64 + lane;
            float* ob = out + ((long)b * KOUT + a) * 4;
            ob[0] = ax1_1; ob[1] = ay1_1; ob[2] = ax2_1; ob[3] = ay2_1;
            out[BDIM * KOUT * 4 + b * KOUT + a] = __uint_as_float((u32)(aky_1 >> 32));
            out[BDIM * KOUT * 5 + b * KOUT + a] = (float)alb_1;
            out[BDIM * KOUT * 6 + b * KOUT + a] = 1.0f;
        }
    }
    for (int a = tid; a < KOUT; a += TN) {
        if (a >= na) {
            float* ob = out + ((long)b * KOUT + a) * 4;
            ob[0] = 0.0f; ob[1] = 0.0f; ob[2] = 0.0f; ob[3] = 0.0f;
            out[BDIM * KOUT * 4 + b * KOUT + a] = 0.0f;
            out[BDIM * KOUT * 5 + b * KOUT + a] = -1.0f;
            out[BDIM * KOUT * 6 + b * KOUT + a] = 0.0f;
        }
    }
}

extern "C" void kernel_launch(void* const* d_in, const int* in_sizes, int n_in,
                              void* d_out, int out_size, void* d_ws, size_t ws_size,
                              hipStream_t stream) {
    const float* logits = (const float*)d_in[0];
    const float* boxreg = (const float*)d_in[1];
    const float* props  = (const float*)d_in[2];
    float* out = (float*)d_out;

    char* ws = (char*)d_ws;
    int* gcount = (int*)(ws + 0);                 // 64 B
    u64* dense  = (u64*)(ws + 1024);              // 16*77824*8 = 9.96 MB

    k_zero<<<1, 64, 0, stream>>>(gcount);
    k_soft<<<(BDIM * NP) / RPB, 256, 0, stream>>>(logits, dense, gcount);
    k_post<<<BDIM, TN, 0, stream>>>(dense, gcount, boxreg, props, out);
}

// Round 16
// 84.177 us; speedup vs baseline: 1.5239x; 1.2611x over previous
//
#include <hip/hip_runtime.h>

typedef unsigned long long u64;
typedef unsigned int u32;

#define BDIM 16
#define NP   4096
#define NC   91
#define NCM1 90
#define MSEL 4096       // top-M per image (reference M)
#define NSORT 1024      // batch-0 sorted prefix size
#define KOUT 100
#define RSLOT 19        // max candidates per row (scores sum to 1, >0.05 => <=19)
#define CAP_D (NP * RSLOT)   // 77824: provable per-image max -> no overflow possible
#define SCORE_T 0.05f
#define NMS_T   0.5f
#define OFFSETF 10000.0f
#define DW_CLAMP_F 4.135166556742356f
#define WF 1333.0f
#define HF 800.0f
#define GTMIN 384        // early-exit floor for approx upper-set select

#define TN 1024
#define RPB 64            // rows per k_soft block (64 blocks per image)

// decode expressions (round-6..15 verified, byte-identical)
#define DECODE_BODY(kvar, bvar, BOXDST, PACKDST)                                   \
    {                                                                              \
        int flat = (int)(~(u32)(kvar));                                            \
        int nidx = flat / NCM1;                                                    \
        int c    = flat - nidx * NCM1 + 1;                                         \
        const float* pr = props + ((long)(bvar) * NP + nidx) * 4;                  \
        float x1 = pr[0], y1 = pr[1], x2 = pr[2], y2 = pr[3];                      \
        float w = x2 - x1, h = y2 - y1;                                            \
        float cx = x1 + 0.5f * w, cy = y1 + 0.5f * h;                              \
        const float* rr = boxreg + (((long)(bvar) * NP + nidx) * NC + c) * 4;      \
        float dx = rr[0] / 10.0f, dy = rr[1] / 10.0f;                              \
        float dw = fminf(rr[2] / 5.0f, DW_CLAMP_F);                                \
        float dh = fminf(rr[3] / 5.0f, DW_CLAMP_F);                                \
        float pcx = __fadd_rn(__fmul_rn(dx, w), cx);                               \
        float pcy = __fadd_rn(__fmul_rn(dy, h), cy);                               \
        float pw  = __fmul_rn(expf(dw), w);                                        \
        float ph2 = __fmul_rn(expf(dh), h);                                        \
        float bx1 = fminf(fmaxf(pcx - 0.5f * pw, 0.0f), WF);                       \
        float by1 = fminf(fmaxf(pcy - 0.5f * ph2, 0.0f), HF);                      \
        float bx2 = fminf(fmaxf(pcx + 0.5f * pw, 0.0f), WF);                       \
        float by2 = fminf(fmaxf(pcy + 0.5f * ph2, 0.0f), HF);                      \
        BOXDST = make_float4(bx1, by1, bx2, by2);                                  \
        float offB = (float)c * OFFSETF;                                           \
        float ox1 = bx1 + offB, oy1 = by1 + offB;                                  \
        float ox2 = bx2 + offB, oy2 = by2 + offB;                                  \
        PACKDST = make_float2((ox2 - ox1) * (oy2 - oy1), (float)c);                \
    }

// ---------------- Kernel 0: zero the 16 per-image counters ----------------
__global__ __launch_bounds__(64) void k_zero(int* __restrict__ gcount) {
    if (threadIdx.x < BDIM) gcount[threadIdx.x] = 0;
}

// ---------------- Kernel 1: softmax -> dense candidates (round-10/12/15 verified) ----------------
__global__ __launch_bounds__(256) void k_soft(const float* __restrict__ logits,
                                              u64* __restrict__ dense,
                                              int* __restrict__ gcount) {
    __shared__ u64 stage[RPB * RSLOT];
    __shared__ int s_cnt, s_base;

    int blk  = blockIdx.x;
    int b    = blk >> 6;
    int lane = threadIdx.x & 63;
    int wid  = threadIdx.x >> 6;

    if (threadIdx.x == 0) s_cnt = 0;
    __syncthreads();

    u64 lm = (1ull << lane) - 1ull;
    for (int it = 0; it < RPB / 4; ++it) {
        int row = blk * RPB + it * 4 + wid;
        const float* lg = logits + (long)row * NC;

        float v0 = lg[lane];
        float v1 = (lane < NC - 64) ? lg[64 + lane] : -3.0e38f;
        float mx = fmaxf(v0, v1);
#pragma unroll
        for (int s = 32; s; s >>= 1) mx = fmaxf(mx, __shfl_xor(mx, s));
        float e0 = expf(v0 - mx);
        float e1 = (lane < NC - 64) ? expf(v1 - mx) : 0.0f;
        float sum = e0 + e1;
#pragma unroll
        for (int s = 32; s; s >>= 1) sum += __shfl_xor(sum, s);

        float s0 = e0 / sum;
        float s1 = e1 / sum;

        int n = row & (NP - 1);
        bool p0 = (lane >= 1) && (s0 > SCORE_T);
        bool p1 = (lane < NC - 64) && (s1 > SCORE_T);
        u64 m0 = __ballot(p0);
        u64 m1 = __ballot(p1);
        int c0  = __popcll(m0);
        int cnt = c0 + __popcll(m1);

        int base = 0;
        if (lane == 0 && cnt) base = atomicAdd(&s_cnt, cnt);
        base = __shfl(base, 0);
        if (p0) {
            int pos  = base + __popcll(m0 & lm);
            int flat = n * NCM1 + (lane - 1);
            stage[pos] = ((u64)__float_as_uint(s0) << 32) | (u32)(~(u32)flat);
        }
        if (p1) {
            int pos  = base + c0 + __popcll(m1 & lm);
            int flat = n * NCM1 + (64 + lane - 1);
            stage[pos] = ((u64)__float_as_uint(s1) << 32) | (u32)(~(u32)flat);
        }
    }
    __syncthreads();

    if (threadIdx.x == 0) s_base = atomicAdd(&gcount[b], s_cnt);
    __syncthreads();
    int m = s_cnt, base = s_base;
    u64* kb = dense + (long)b * CAP_D + base;
    for (int i = threadIdx.x; i < m; i += 256) kb[i] = stage[i];
}

// ---------------- exact radix rank-select (round-8/10/12/15 verified body) ----------------
__device__ __forceinline__ u64 radix_rank(const u64* __restrict__ kb, int n, int rank,
                                          int* hist, int* p_sel, int* p_gt, int tid) {
    u64 prefix = 0, mask = 0;
    const int shifts[6] = {53, 42, 31, 20, 10, 0};
    const int bitsv [6] = {11, 11, 11, 11, 10, 10};

    for (int pass = 0; pass < 6; ++pass) {
        int shift = shifts[pass];
        int nb = 1 << bitsv[pass];
        if (tid < nb) hist[tid] = 0;
        if (tid + 1024 < nb) hist[tid + 1024] = 0;
        __syncthreads();
        for (int i = tid; i < n; i += 1024) {
            u64 k = kb[i];
            if ((k & mask) == prefix)
                atomicAdd(&hist[(int)((k >> shift) & (u64)(nb - 1))], 1);
        }
        __syncthreads();
        for (int d = 1; d < nb; d <<= 1) {
            int v0 = 0, v1 = 0;
            if (tid < nb && tid + d < nb) v0 = hist[tid + d];
            if (tid + 1024 < nb && tid + 1024 + d < nb) v1 = hist[tid + 1024 + d];
            __syncthreads();
            if (tid < nb) hist[tid] += v0;
            if (tid + 1024 < nb) hist[tid + 1024] += v1;
            __syncthreads();
        }
        for (int j = tid; j < nb; j += 1024) {
            int c  = hist[j];
            int cn = (j + 1 < nb) ? hist[j + 1] : 0;
            if (c >= rank && cn < rank) { *p_sel = j; *p_gt = cn; }
        }
        __syncthreads();
        prefix |= ((u64)(*p_sel)) << shift;
        mask   |= ((u64)(nb - 1)) << shift;
        rank   -= *p_gt;
        __syncthreads();
    }
    return prefix;   // uniform across block
}

// ---------------- approx upper-set select: same passes, EARLY EXIT ----------------
// Returns threshold Bthr such that S = {k : k >= Bthr} is upward-closed with
// |S| = rank0 - rank_remaining in [GTMIN, rank0) (or exact rank0 at final pass).
// Any upward-closed S is a valid batch-0: sorted(S) is a prefix of the global
// sorted visit order; exact-T fallback preserves MSEL semantics.
__device__ __forceinline__ u64 radix_upper(const u64* __restrict__ kb, int n, int rank,
                                           int* hist, int* p_sel, int* p_gt, int tid) {
    int rank0 = rank;
    u64 prefix = 0, mask = 0;
    const int shifts[6] = {53, 42, 31, 20, 10, 0};
    const int bitsv [6] = {11, 11, 11, 11, 10, 10};

    for (int pass = 0; pass < 6; ++pass) {
        int shift = shifts[pass];
        int nb = 1 << bitsv[pass];
        if (tid < nb) hist[tid] = 0;
        if (tid + 1024 < nb) hist[tid + 1024] = 0;
        __syncthreads();
        for (int i = tid; i < n; i += 1024) {
            u64 k = kb[i];
            if ((k & mask) == prefix)
                atomicAdd(&hist[(int)((k >> shift) & (u64)(nb - 1))], 1);
        }
        __syncthreads();
        for (int d = 1; d < nb; d <<= 1) {
            int v0 = 0, v1 = 0;
            if (tid < nb && tid + d < nb) v0 = hist[tid + d];
            if (tid + 1024 < nb && tid + 1024 + d < nb) v1 = hist[tid + 1024 + d];
            __syncthreads();
            if (tid < nb) hist[tid] += v0;
            if (tid + 1024 < nb) hist[tid + 1024] += v1;
            __syncthreads();
        }
        for (int j = tid; j < nb; j += 1024) {
            int c  = hist[j];
            int cn = (j + 1 < nb) ? hist[j + 1] : 0;
            if (c >= rank && cn < rank) { *p_sel = j; *p_gt = cn; }
        }
        __syncthreads();
        int sel = *p_sel, gt = *p_gt;
        rank -= gt;
        __syncthreads();
        // keys strictly above the selected bin across all passes so far:
        // count = rank0 - rank; threshold = prefix + (sel+1)<<shift (carry-safe '+')
        if (pass < 5) {
            if (rank0 - rank >= GTMIN)
                return prefix + ((u64)(sel + 1) << shift);
            prefix |= ((u64)sel) << shift;
            mask   |= ((u64)(nb - 1)) << shift;
        } else {
            prefix |= ((u64)sel) << shift;   // exact rank0-th key; {k>=prefix} = rank0 keys
        }
    }
    return prefix;
}

// ---------------- Kernel 2: fused select + gather + sort + decode + walk NMS ----------------
__global__ __launch_bounds__(TN) void k_post(const u64* __restrict__ dense,
                                             const int* __restrict__ gcount,
                                             const float* __restrict__ boxreg,
                                             const float* __restrict__ props,
                                             float* __restrict__ out) {
    __shared__ __align__(16) char ldsbuf[131072];   // aliased phases, 128 KB
    __shared__ int s_cnt, s_nacc, s_sel, s_gt;

    // batch-0 layout
    float4* sbox  = (float4*)ldsbuf;                // 16 KB (1024)
    float2* spack = (float2*)(ldsbuf + 16384);      //  8 KB
    u64*    skey  = (u64*)(ldsbuf + 24576);         //  8 KB
    int*    hist  = (int*)(ldsbuf + 32768);         //  8 KB

    int b = blockIdx.x, tid = threadIdx.x;
    int lane = tid & 63, wid = tid >> 6;
    int n = gcount[b]; if (n > CAP_D) n = CAP_D;
    const u64* kb = dense + (long)b * CAP_D;
    u64 lm = (1ull << lane) - 1ull;
    int npad = (n + TN - 1) & ~(TN - 1);

    // ---- Bthr: upward-closed batch-0 threshold (0 => take all) ----
    u64 Bthr = 0ull;
    if (n > NSORT) Bthr = radix_upper(kb, n, NSORT, hist, &s_sel, &s_gt, tid);

    // ---- gather batch-0: keys >= Bthr (round-8/12/15 verified pattern) ----
    skey[tid] = 0ull;
    if (tid == 0) s_cnt = 0;
    __syncthreads();
    for (int i0 = tid; i0 < npad; i0 += TN) {
        bool inb = (i0 < n);
        u64 k = inb ? kb[i0] : 0ull;
        bool pred = inb && (k >= Bthr);
        u64 mb_ = __ballot(pred);
        int cnt = __popcll(mb_);
        int bp = 0;
        if (lane == 0 && cnt) bp = atomicAdd(&s_cnt, cnt);
        bp = __shfl(bp, 0);
        if (pred) {
            int pos = bp + __popcll(mb_ & lm);
            if (pos < NSORT) skey[pos] = k;
        }
    }
    __syncthreads();
    int mb = s_cnt; if (mb > NSORT) mb = NSORT;

    // ---- register bitonic sort desc over 1024 (round-8/12/15 verified) ----
    {
        u64 r = skey[tid];
        for (int kk = 2; kk <= NSORT; kk <<= 1) {
            for (int j = kk >> 1; j; j >>= 1) {
                u64 p;
                if (j >= 64) {
                    skey[tid] = r;
                    __syncthreads();
                    p = skey[tid ^ j];
                    __syncthreads();
                } else {
                    p = __shfl_xor(r, j);
                }
                bool lower = (tid & j) == 0;
                bool desc  = ((tid & kk) == 0);
                u64 mx = (r > p) ? r : p;
                u64 mn = (r > p) ? p : r;
                r = (lower == desc) ? mx : mn;
            }
        }
        skey[tid] = r;
        __syncthreads();
    }

    // ---- decode sorted candidates (all 16 waves, scattered loads in parallel) ----
    for (int i = tid; i < mb; i += TN) {
        u64 k = skey[i];
        float4 bx; float2 pk;
        DECODE_BODY(k, b, bx, pk);
        sbox[i] = bx;
        spack[i] = pk;
    }
    __syncthreads();

    // accepted list: wave-0 lane registers, 2 slots/lane (round-8/12/15 verified)
    float ax1_0 = 0, ay1_0 = 0, ax2_0 = 0, ay2_0 = 0, aar_0 = 0;
    float ax1_1 = 0, ay1_1 = 0, ax2_1 = 0, ay2_1 = 0, aar_1 = 0;
    int alb_0 = -1, alb_1 = -1;
    u64 aky_0 = 0, aky_1 = 0;
    int nacc = 0;

    // ---- serial walk in sorted order (round-8/12/15 verified text) ----
    if (wid == 0) {
        float4 Bv = sbox[0];
        float2 pk = spack[0];
        u64    ck = skey[0];
        for (int i = 0; i < mb && nacc < KOUT; ++i) {
            int ip = (i + 1 < mb) ? i + 1 : i;
            float4 nBv = sbox[ip];
            float2 npk = spack[ip];
            u64    nck = skey[ip];

            float areaB = pk.x;
            float labf  = pk.y;
            float off   = __fmul_rn(labf, OFFSETF);
            bool conf = false;
            if (lane < nacc && (float)alb_0 == labf) {
                float op1x = __fadd_rn(fminf(ax2_0, Bv.z), off);
                float op2x = __fadd_rn(fmaxf(ax1_0, Bv.x), off);
                float iw = fmaxf(op1x - op2x, 0.0f);
                float op1y = __fadd_rn(fminf(ay2_0, Bv.w), off);
                float op2y = __fadd_rn(fmaxf(ay1_0, Bv.y), off);
                float ih = fmaxf(op1y - op2y, 0.0f);
                float inter = iw * ih;
                float denom = areaB + aar_0 - inter + 1e-9f;
                if (inter / denom > NMS_T) conf = true;
            }
            if (64 + lane < nacc && (float)alb_1 == labf) {
                float op1x = __fadd_rn(fminf(ax2_1, Bv.z), off);
                float op2x = __fadd_rn(fmaxf(ax1_1, Bv.x), off);
                float iw = fmaxf(op1x - op2x, 0.0f);
                float op1y = __fadd_rn(fminf(ay2_1, Bv.w), off);
                float op2y = __fadd_rn(fmaxf(ay1_1, Bv.y), off);
                float ih = fmaxf(op1y - op2y, 0.0f);
                float inter = iw * ih;
                float denom = areaB + aar_1 - inter + 1e-9f;
                if (inter / denom > NMS_T) conf = true;
            }
            if (__ballot(conf) == 0ull) {
                if (nacc < 64) {
                    if (lane == nacc) {
                        ax1_0 = Bv.x; ay1_0 = Bv.y; ax2_0 = Bv.z; ay2_0 = Bv.w;
                        aar_0 = areaB; alb_0 = (int)labf; aky_0 = ck;
                    }
                } else {
                    if (lane == nacc - 64) {
                        ax1_1 = Bv.x; ay1_1 = Bv.y; ax2_1 = Bv.z; ay2_1 = Bv.w;
                        aar_1 = areaB; alb_1 = (int)labf; aky_1 = ck;
                    }
                }
                ++nacc;
            }
            Bv = nBv; pk = npk; ck = nck;
        }
        if (lane == 0) s_nacc = nacc;
    }
    __syncthreads();

    // ---- exact fallback: remaining ranks up to MSEL (rare; lazy exact T) ----
    if (s_nacc < KOUT && Bthr != 0ull) {
        u64 T = 0ull;
        if (n > MSEL) T = radix_rank(kb, n, MSEL, hist, &s_sel, &s_gt, tid);

        u64*    fkey  = (u64*)ldsbuf;               // 32 KB (4096)
        float4* fbox  = (float4*)(ldsbuf + 32768);  // 64 KB
        float2* fpack = (float2*)(ldsbuf + 98304);  // 32 KB

        for (int i = tid; i < MSEL; i += TN) fkey[i] = 0ull;
        if (tid == 0) s_cnt = 0;
        __syncthreads();
        for (int i0 = tid; i0 < npad; i0 += TN) {
            bool inb = (i0 < n);
            u64 k = inb ? kb[i0] : 0ull;
            bool pred = inb && (k >= T && k < Bthr);
            u64 mb_ = __ballot(pred);
            int cnt = __popcll(mb_);
            int bp = 0;
            if (lane == 0 && cnt) bp = atomicAdd(&s_cnt, cnt);
            bp = __shfl(bp, 0);
            if (pred) {
                int pos = bp + __popcll(mb_ & lm);
                if (pos < MSEL) fkey[pos] = k;
            }
        }
        __syncthreads();
        int mb2 = s_cnt; if (mb2 > MSEL) mb2 = MSEL;

        for (int kk = 2; kk <= MSEL; kk <<= 1) {
            for (int j = kk >> 1; j > 0; j >>= 1) {
                for (int t = tid; t < MSEL; t += TN) {
                    int l = t ^ j;
                    if (l > t) {
                        u64 a = fkey[t], c = fkey[l];
                        bool up = ((t & kk) == 0);
                        bool sw = up ? (a < c) : (a > c);
                        if (sw) { fkey[t] = c; fkey[l] = a; }
                    }
                }
                __syncthreads();
            }
        }

        for (int i = tid; i < mb2; i += TN) {
            u64 k = fkey[i];
            float4 bx; float2 pk;
            DECODE_BODY(k, b, bx, pk);
            fbox[i] = bx;
            fpack[i] = pk;
        }
        __syncthreads();

        if (wid == 0) {
            float4 Bv = fbox[0];
            float2 pk = fpack[0];
            u64    ck = fkey[0];
            for (int i = 0; i < mb2 && nacc < KOUT; ++i) {
                int ip = (i + 1 < mb2) ? i + 1 : i;
                float4 nBv = fbox[ip];
                float2 npk = fpack[ip];
                u64    nck = fkey[ip];

                float areaB = pk.x;
                float labf  = pk.y;
                float off   = __fmul_rn(labf, OFFSETF);
                bool conf = false;
                if (lane < nacc && (float)alb_0 == labf) {
                    float op1x = __fadd_rn(fminf(ax2_0, Bv.z), off);
                    float op2x = __fadd_rn(fmaxf(ax1_0, Bv.x), off);
                    float iw = fmaxf(op1x - op2x, 0.0f);
                    float op1y = __fadd_rn(fminf(ay2_0, Bv.w), off);
                    float op2y = __fadd_rn(fmaxf(ay1_0, Bv.y), off);
                    float ih = fmaxf(op1y - op2y, 0.0f);
                    float inter = iw * ih;
                    float denom = areaB + aar_0 - inter + 1e-9f;
                    if (inter / denom > NMS_T) conf = true;
                }
                if (64 + lane < nacc && (float)alb_1 == labf) {
                    float op1x = __fadd_rn(fminf(ax2_1, Bv.z), off);
                    float op2x = __fadd_rn(fmaxf(ax1_1, Bv.x), off);
                    float iw = fmaxf(op1x - op2x, 0.0f);
                    float op1y = __fadd_rn(fminf(ay2_1, Bv.w), off);
                    float op2y = __fadd_rn(fmaxf(ay1_1, Bv.y), off);
                    float ih = fmaxf(op1y - op2y, 0.0f);
                    float inter = iw * ih;
                    float denom = areaB + aar_1 - inter + 1e-9f;
                    if (inter / denom > NMS_T) conf = true;
                }
                if (__ballot(conf) == 0ull) {
                    if (nacc < 64) {
                        if (lane == nacc) {
                            ax1_0 = Bv.x; ay1_0 = Bv.y; ax2_0 = Bv.z; ay2_0 = Bv.w;
                            aar_0 = areaB; alb_0 = (int)labf; aky_0 = ck;
                        }
                    } else {
                        if (lane == nacc - 64) {
                            ax1_1 = Bv.x; ay1_1 = Bv.y; ax2_1 = Bv.z; ay2_1 = Bv.w;
                            aar_1 = areaB; alb_1 = (int)labf; aky_1 = ck;
                        }
                    }
                    ++nacc;
                }
                Bv = nBv; pk = npk; ck = nck;
            }
            if (lane == 0) s_nacc = nacc;
        }
        __syncthreads();
    }

    // ---- emit outputs in acceptance order (round-8/12/15 verified) ----
    int na = s_nacc; if (na > KOUT) na = KOUT;
    if (wid == 0) {
        if (lane < na) {
            int a = lane;
            float* ob = out + ((long)b * KOUT + a) * 4;
            ob[0] = ax1_0; ob[1] = ay1_0; ob[2] = ax2_0; ob[3] = ay2_0;
            out[BDIM * KOUT * 4 + b * KOUT + a] = __uint_as_float((u32)(aky_0 >> 32));
            out[BDIM * KOUT * 5 + b * KOUT + a] = (float)alb_0;
            out[BDIM * KOUT * 6 + b * KOUT + a] = 1.0f;
        }
        if (64 + lane < na) {
            int a = 64 + lane;
            float* ob = out + ((long)b * KOUT + a) * 4;
            ob[0] = ax1_1; ob[1] = ay1_1; ob[2] = ax2_1; ob[3] = ay2_1;
            out[BDIM * KOUT * 4 + b * KOUT + a] = __uint_as_float((u32)(aky_1 >> 32));
            out[BDIM * KOUT * 5 + b * KOUT + a] = (float)alb_1;
            out[BDIM * KOUT * 6 + b * KOUT + a] = 1.0f;
        }
    }
    for (int a = tid; a < KOUT; a += TN) {
        if (a >= na) {
            float* ob = out + ((long)b * KOUT + a) * 4;
            ob[0] = 0.0f; ob[1] = 0.0f; ob[2] = 0.0f; ob[3] = 0.0f;
            out[BDIM * KOUT * 4 + b * KOUT + a] = 0.0f;
            out[BDIM * KOUT * 5 + b * KOUT + a] = -1.0f;
            out[BDIM * KOUT * 6 + b * KOUT + a] = 0.0f;
        }
    }
}

extern "C" void kernel_launch(void* const* d_in, const int* in_sizes, int n_in,
                              void* d_out, int out_size, void* d_ws, size_t ws_size,
                              hipStream_t stream) {
    const float* logits = (const float*)d_in[0];
    const float* boxreg = (const float*)d_in[1];
    const float* props  = (const float*)d_in[2];
    float* out = (float*)d_out;

    char* ws = (char*)d_ws;
    int* gcount = (int*)(ws + 0);                 // 64 B
    u64* dense  = (u64*)(ws + 1024);              // 16*77824*8 = 9.96 MB

    k_zero<<<1, 64, 0, stream>>>(gcount);
    k_soft<<<(BDIM * NP) / RPB, 256, 0, stream>>>(logits, dense, gcount);
    k_post<<<BDIM, TN, 0, stream>>>(dense, gcount, boxreg, props, out);
}

// Round 17
// 78.552 us; speedup vs baseline: 1.6330x; 1.0716x over previous
//
#include <hip/hip_runtime.h>

typedef unsigned long long u64;
typedef unsigned int u32;

#define BDIM 16
#define NP   4096
#define NC   91
#define NCM1 90
#define MSEL 4096       // top-M per image (reference M)
#define NSORT 1024      // batch-0 sorted prefix size
#define KOUT 100
#define RSLOT 19        // max candidates per row (scores sum to 1, >0.05 => <=19)
#define CAP_D (NP * RSLOT)   // 77824: provable per-image max -> no overflow possible
#define SCORE_T 0.05f
#define NMS_T   0.5f
#define OFFSETF 10000.0f
#define DW_CLAMP_F 4.135166556742356f
#define WF 1333.0f
#define HF 800.0f
#define GTMIN 384        // early-exit floor for approx upper-set select
#define HCAP 4096        // per-image hot-array capacity (score >= 0.25)
#define FKEY (((u64)0x3E800000u) << 32)   // key of score 0.25 (flat=0)

#define TN 1024
#define RPB 64            // rows per k_soft block (64 blocks per image)

// decode expressions (round-6..16 verified, byte-identical)
#define DECODE_BODY(kvar, bvar, BOXDST, PACKDST)                                   \
    {                                                                              \
        int flat = (int)(~(u32)(kvar));                                            \
        int nidx = flat / NCM1;                                                    \
        int c    = flat - nidx * NCM1 + 1;                                         \
        const float* pr = props + ((long)(bvar) * NP + nidx) * 4;                  \
        float x1 = pr[0], y1 = pr[1], x2 = pr[2], y2 = pr[3];                      \
        float w = x2 - x1, h = y2 - y1;                                            \
        float cx = x1 + 0.5f * w, cy = y1 + 0.5f * h;                              \
        const float* rr = boxreg + (((long)(bvar) * NP + nidx) * NC + c) * 4;      \
        float dx = rr[0] / 10.0f, dy = rr[1] / 10.0f;                              \
        float dw = fminf(rr[2] / 5.0f, DW_CLAMP_F);                                \
        float dh = fminf(rr[3] / 5.0f, DW_CLAMP_F);                                \
        float pcx = __fadd_rn(__fmul_rn(dx, w), cx);                               \
        float pcy = __fadd_rn(__fmul_rn(dy, h), cy);                               \
        float pw  = __fmul_rn(expf(dw), w);                                        \
        float ph2 = __fmul_rn(expf(dh), h);                                        \
        float bx1 = fminf(fmaxf(pcx - 0.5f * pw, 0.0f), WF);                       \
        float by1 = fminf(fmaxf(pcy - 0.5f * ph2, 0.0f), HF);                      \
        float bx2 = fminf(fmaxf(pcx + 0.5f * pw, 0.0f), WF);                       \
        float by2 = fminf(fmaxf(pcy + 0.5f * ph2, 0.0f), HF);                      \
        BOXDST = make_float4(bx1, by1, bx2, by2);                                  \
        float offB = (float)c * OFFSETF;                                           \
        float ox1 = bx1 + offB, oy1 = by1 + offB;                                  \
        float ox2 = bx2 + offB, oy2 = by2 + offB;                                  \
        PACKDST = make_float2((ox2 - ox1) * (oy2 - oy1), (float)c);                \
    }

// ---------------- Kernel 0: zero counters + per-image histograms ----------------
__global__ __launch_bounds__(1024) void k_zero(int* __restrict__ gcount,
                                               int* __restrict__ hcnt,
                                               int* __restrict__ ghist) {
    int blk = blockIdx.x;
    if (blk == 0) {
        if (threadIdx.x < BDIM) gcount[threadIdx.x] = 0;
        if (threadIdx.x >= 64 && threadIdx.x < 64 + BDIM) hcnt[threadIdx.x - 64] = 0;
    } else {
        int* g = ghist + (blk - 1) * 2048;
        for (int i = threadIdx.x; i < 2048; i += 1024) g[i] = 0;
    }
}

// ---------------- Kernel 1: softmax -> dense + hot(score>=0.25) + score histogram ----------------
__global__ __launch_bounds__(256) void k_soft(const float* __restrict__ logits,
                                              u64* __restrict__ dense,
                                              int* __restrict__ gcount,
                                              u64* __restrict__ hot,
                                              int* __restrict__ hcnt,
                                              int* __restrict__ ghist) {
    __shared__ u64 stage[RPB * RSLOT];
    __shared__ u64 hstage[256];          // provable cap: <=4 per row (scores sum to 1)
    __shared__ int lhist[2048];
    __shared__ int s_cnt, s_base, s_hcnt, s_hbase;

    int blk  = blockIdx.x;
    int b    = blk >> 6;
    int lane = threadIdx.x & 63;
    int wid  = threadIdx.x >> 6;

    if (threadIdx.x == 0) { s_cnt = 0; s_hcnt = 0; }
    for (int i = threadIdx.x; i < 2048; i += 256) lhist[i] = 0;
    __syncthreads();

    u64 lm = (1ull << lane) - 1ull;
    for (int it = 0; it < RPB / 4; ++it) {
        int row = blk * RPB + it * 4 + wid;
        const float* lg = logits + (long)row * NC;

        float v0 = lg[lane];
        float v1 = (lane < NC - 64) ? lg[64 + lane] : -3.0e38f;
        float mx = fmaxf(v0, v1);
#pragma unroll
        for (int s = 32; s; s >>= 1) mx = fmaxf(mx, __shfl_xor(mx, s));
        float e0 = expf(v0 - mx);
        float e1 = (lane < NC - 64) ? expf(v1 - mx) : 0.0f;
        float sum = e0 + e1;
#pragma unroll
        for (int s = 32; s; s >>= 1) sum += __shfl_xor(sum, s);

        float s0 = e0 / sum;
        float s1 = e1 / sum;

        int n = row & (NP - 1);
        bool p0 = (lane >= 1) && (s0 > SCORE_T);
        bool p1 = (lane < NC - 64) && (s1 > SCORE_T);
        u64 key0 = ((u64)__float_as_uint(s0) << 32) | (u32)(~(u32)(n * NCM1 + (lane - 1)));
        u64 key1 = ((u64)__float_as_uint(s1) << 32) | (u32)(~(u32)(n * NCM1 + (64 + lane - 1)));
        u64 m0 = __ballot(p0);
        u64 m1 = __ballot(p1);
        int c0  = __popcll(m0);
        int cnt = c0 + __popcll(m1);

        int base = 0;
        if (lane == 0 && cnt) base = atomicAdd(&s_cnt, cnt);
        base = __shfl(base, 0);
        if (p0) {
            stage[base + __popcll(m0 & lm)] = key0;
            atomicAdd(&lhist[(int)(key0 >> 53)], 1);
        }
        if (p1) {
            stage[base + c0 + __popcll(m1 & lm)] = key1;
            atomicAdd(&lhist[(int)(key1 >> 53)], 1);
        }

        // hot subset: score >= 0.25 (<=4/row provable)
        bool q0 = p0 && (s0 >= 0.25f);
        bool q1 = p1 && (s1 >= 0.25f);
        u64 h0 = __ballot(q0);
        u64 h1 = __ballot(q1);
        int hc0 = __popcll(h0);
        int hrow = hc0 + __popcll(h1);
        int hb = 0;
        if (lane == 0 && hrow) hb = atomicAdd(&s_hcnt, hrow);
        hb = __shfl(hb, 0);
        if (q0) hstage[hb + __popcll(h0 & lm)] = key0;
        if (q1) hstage[hb + hc0 + __popcll(h1 & lm)] = key1;
    }
    __syncthreads();

    if (threadIdx.x == 0) {
        s_base  = atomicAdd(&gcount[b], s_cnt);
        s_hbase = atomicAdd(&hcnt[b], s_hcnt);
    }
    __syncthreads();
    int m = s_cnt, base = s_base;
    u64* kb = dense + (long)b * CAP_D + base;
    for (int i = threadIdx.x; i < m; i += 256) kb[i] = stage[i];
    int hm = s_hcnt, hb2 = s_hbase;
    u64* hbp = hot + (long)b * HCAP;
    for (int i = threadIdx.x; i < hm; i += 256) {
        int pos = hb2 + i;
        if (pos < HCAP) hbp[pos] = hstage[i];
    }
    for (int i = threadIdx.x; i < 2048; i += 256) {
        int v = lhist[i];
        if (v) atomicAdd(&ghist[b * 2048 + i], v);
    }
}

// ---------------- exact radix rank-select (round-8..16 verified body) ----------------
__device__ __forceinline__ u64 radix_rank(const u64* __restrict__ kb, int n, int rank,
                                          int* hist, int* p_sel, int* p_gt, int tid) {
    u64 prefix = 0, mask = 0;
    const int shifts[6] = {53, 42, 31, 20, 10, 0};
    const int bitsv [6] = {11, 11, 11, 11, 10, 10};

    for (int pass = 0; pass < 6; ++pass) {
        int shift = shifts[pass];
        int nb = 1 << bitsv[pass];
        if (tid < nb) hist[tid] = 0;
        if (tid + 1024 < nb) hist[tid + 1024] = 0;
        __syncthreads();
        for (int i = tid; i < n; i += 1024) {
            u64 k = kb[i];
            if ((k & mask) == prefix)
                atomicAdd(&hist[(int)((k >> shift) & (u64)(nb - 1))], 1);
        }
        __syncthreads();
        for (int d = 1; d < nb; d <<= 1) {
            int v0 = 0, v1 = 0;
            if (tid < nb && tid + d < nb) v0 = hist[tid + d];
            if (tid + 1024 < nb && tid + 1024 + d < nb) v1 = hist[tid + 1024 + d];
            __syncthreads();
            if (tid < nb) hist[tid] += v0;
            if (tid + 1024 < nb) hist[tid + 1024] += v1;
            __syncthreads();
        }
        for (int j = tid; j < nb; j += 1024) {
            int c  = hist[j];
            int cn = (j + 1 < nb) ? hist[j + 1] : 0;
            if (c >= rank && cn < rank) { *p_sel = j; *p_gt = cn; }
        }
        __syncthreads();
        prefix |= ((u64)(*p_sel)) << shift;
        mask   |= ((u64)(nb - 1)) << shift;
        rank   -= *p_gt;
        __syncthreads();
    }
    return prefix;
}

// ---------------- approx upper-set select over keys (round-16 verified; fallback only) ----------------
__device__ __forceinline__ u64 radix_upper(const u64* __restrict__ kb, int n, int rank,
                                           int* hist, int* p_sel, int* p_gt, int tid) {
    int rank0 = rank;
    u64 prefix = 0, mask = 0;
    const int shifts[6] = {53, 42, 31, 20, 10, 0};
    const int bitsv [6] = {11, 11, 11, 11, 10, 10};

    for (int pass = 0; pass < 6; ++pass) {
        int shift = shifts[pass];
        int nb = 1 << bitsv[pass];
        if (tid < nb) hist[tid] = 0;
        if (tid + 1024 < nb) hist[tid + 1024] = 0;
        __syncthreads();
        for (int i = tid; i < n; i += 1024) {
            u64 k = kb[i];
            if ((k & mask) == prefix)
                atomicAdd(&hist[(int)((k >> shift) & (u64)(nb - 1))], 1);
        }
        __syncthreads();
        for (int d = 1; d < nb; d <<= 1) {
            int v0 = 0, v1 = 0;
            if (tid < nb && tid + d < nb) v0 = hist[tid + d];
            if (tid + 1024 < nb && tid + 1024 + d < nb) v1 = hist[tid + 1024 + d];
            __syncthreads();
            if (tid < nb) hist[tid] += v0;
            if (tid + 1024 < nb) hist[tid + 1024] += v1;
            __syncthreads();
        }
        for (int j = tid; j < nb; j += 1024) {
            int c  = hist[j];
            int cn = (j + 1 < nb) ? hist[j + 1] : 0;
            if (c >= rank && cn < rank) { *p_sel = j; *p_gt = cn; }
        }
        __syncthreads();
        int sel = *p_sel, gt = *p_gt;
        rank -= gt;
        __syncthreads();
        if (pass < 5) {
            if (rank0 - rank >= GTMIN)
                return prefix + ((u64)(sel + 1) << shift);
            prefix |= ((u64)sel) << shift;
            mask   |= ((u64)(nb - 1)) << shift;
        } else {
            prefix |= ((u64)sel) << shift;
        }
    }
    return prefix;
}

// ---------------- Kernel 2: fused select(hist) + gather(hot) + sort + decode + walk ----------------
__global__ __launch_bounds__(TN) void k_post(const u64* __restrict__ dense,
                                             const int* __restrict__ gcount,
                                             const u64* __restrict__ hot,
                                             const int* __restrict__ hcnt,
                                             const int* __restrict__ ghist,
                                             const float* __restrict__ boxreg,
                                             const float* __restrict__ props,
                                             float* __restrict__ out) {
    __shared__ __align__(16) char ldsbuf[131072];   // aliased phases, 128 KB
    __shared__ int s_cnt, s_nacc, s_sel, s_gt;

    // batch-0 layout
    float4* sbox  = (float4*)ldsbuf;                // 16 KB (1024)
    float2* spack = (float2*)(ldsbuf + 16384);      //  8 KB
    u64*    skey  = (u64*)(ldsbuf + 24576);         //  8 KB
    int*    hist  = (int*)(ldsbuf + 32768);         //  8 KB

    int b = blockIdx.x, tid = threadIdx.x;
    int lane = tid & 63, wid = tid >> 6;
    int n = gcount[b]; if (n > CAP_D) n = CAP_D;
    const u64* kb = dense + (long)b * CAP_D;
    u64 lm = (1ull << lane) - 1ull;
    int npad = (n + TN - 1) & ~(TN - 1);

    // ---- Bthr from precomputed histogram (no key scan in common path) ----
    u64 Bthr = 0ull;
    bool hist_ok = false;
    if (n > NSORT) {
        for (int i = tid; i < 2048; i += TN) hist[i] = ghist[b * 2048 + i];
        __syncthreads();
        for (int d = 1; d < 2048; d <<= 1) {
            int v0 = 0, v1 = 0;
            if (tid + d < 2048) v0 = hist[tid + d];
            if (tid + 1024 + d < 2048) v1 = hist[tid + 1024 + d];
            __syncthreads();
            hist[tid] += v0;
            if (tid + 1024 + d < 2048 || tid + 1024 < 2048) hist[tid + 1024] += v1;
            __syncthreads();
        }
        for (int j = tid; j < 2048; j += TN) {
            int c  = hist[j];
            int cn = (j + 1 < 2048) ? hist[j + 1] : 0;
            if (c >= NSORT && cn < NSORT) { s_sel = j; s_gt = cn; }
        }
        __syncthreads();
        int sel = s_sel, gt = s_gt;
        __syncthreads();
        if (gt >= GTMIN) { Bthr = ((u64)(sel + 1)) << 53; hist_ok = true; }
        else             Bthr = radix_upper(kb, n, NSORT, hist, &s_sel, &s_gt, tid);
    }
    int hn = hcnt[b];
    bool use_hot = hist_ok && (Bthr >= FKEY) && (hn <= HCAP);

    // ---- gather batch-0: keys >= Bthr (verified aggregation pattern) ----
    skey[tid] = 0ull;
    if (tid == 0) s_cnt = 0;
    __syncthreads();
    if (use_hot) {
        const u64* hb = hot + (long)b * HCAP;
        int hpad = (hn + TN - 1) & ~(TN - 1);
        for (int i0 = tid; i0 < hpad; i0 += TN) {
            bool inb = (i0 < hn);
            u64 k = inb ? hb[i0] : 0ull;
            bool pred = inb && (k >= Bthr);
            u64 mb_ = __ballot(pred);
            int cnt = __popcll(mb_);
            int bp = 0;
            if (lane == 0 && cnt) bp = atomicAdd(&s_cnt, cnt);
            bp = __shfl(bp, 0);
            if (pred) {
                int pos = bp + __popcll(mb_ & lm);
                if (pos < NSORT) skey[pos] = k;
            }
        }
    } else {
        for (int i0 = tid; i0 < npad; i0 += TN) {
            bool inb = (i0 < n);
            u64 k = inb ? kb[i0] : 0ull;
            bool pred = inb && (k >= Bthr);
            u64 mb_ = __ballot(pred);
            int cnt = __popcll(mb_);
            int bp = 0;
            if (lane == 0 && cnt) bp = atomicAdd(&s_cnt, cnt);
            bp = __shfl(bp, 0);
            if (pred) {
                int pos = bp + __popcll(mb_ & lm);
                if (pos < NSORT) skey[pos] = k;
            }
        }
    }
    __syncthreads();
    if (s_cnt > NSORT) {    // safety: only if ghist corrupted -> exact recompute
        Bthr = radix_upper(kb, n, NSORT, hist, &s_sel, &s_gt, tid);
        skey[tid] = 0ull;
        if (tid == 0) s_cnt = 0;
        __syncthreads();
        for (int i0 = tid; i0 < npad; i0 += TN) {
            bool inb = (i0 < n);
            u64 k = inb ? kb[i0] : 0ull;
            bool pred = inb && (k >= Bthr);
            u64 mb_ = __ballot(pred);
            int cnt = __popcll(mb_);
            int bp = 0;
            if (lane == 0 && cnt) bp = atomicAdd(&s_cnt, cnt);
            bp = __shfl(bp, 0);
            if (pred) {
                int pos = bp + __popcll(mb_ & lm);
                if (pos < NSORT) skey[pos] = k;
            }
        }
        __syncthreads();
    }
    int mb = s_cnt; if (mb > NSORT) mb = NSORT;

    // ---- register bitonic sort desc over 1024 (round-8..16 verified) ----
    {
        u64 r = skey[tid];
        for (int kk = 2; kk <= NSORT; kk <<= 1) {
            for (int j = kk >> 1; j; j >>= 1) {
                u64 p;
                if (j >= 64) {
                    skey[tid] = r;
                    __syncthreads();
                    p = skey[tid ^ j];
                    __syncthreads();
                } else {
                    p = __shfl_xor(r, j);
                }
                bool lower = (tid & j) == 0;
                bool desc  = ((tid & kk) == 0);
                u64 mx = (r > p) ? r : p;
                u64 mn = (r > p) ? p : r;
                r = (lower == desc) ? mx : mn;
            }
        }
        skey[tid] = r;
        __syncthreads();
    }

    // ---- decode sorted candidates ----
    for (int i = tid; i < mb; i += TN) {
        u64 k = skey[i];
        float4 bx; float2 pk;
        DECODE_BODY(k, b, bx, pk);
        sbox[i] = bx;
        spack[i] = pk;
    }
    __syncthreads();

    // accepted list: wave-0 lane registers, 2 slots/lane (round-8..16 verified)
    float ax1_0 = 0, ay1_0 = 0, ax2_0 = 0, ay2_0 = 0, aar_0 = 0;
    float ax1_1 = 0, ay1_1 = 0, ax2_1 = 0, ay2_1 = 0, aar_1 = 0;
    int alb_0 = -1, alb_1 = -1;
    u64 aky_0 = 0, aky_1 = 0;
    int nacc = 0;

    // ---- serial walk in sorted order (round-8..16 verified text) ----
    if (wid == 0) {
        float4 Bv = sbox[0];
        float2 pk = spack[0];
        u64    ck = skey[0];
        for (int i = 0; i < mb && nacc < KOUT; ++i) {
            int ip = (i + 1 < mb) ? i + 1 : i;
            float4 nBv = sbox[ip];
            float2 npk = spack[ip];
            u64    nck = skey[ip];

            float areaB = pk.x;
            float labf  = pk.y;
            float off   = __fmul_rn(labf, OFFSETF);
            bool conf = false;
            if (lane < nacc && (float)alb_0 == labf) {
                float op1x = __fadd_rn(fminf(ax2_0, Bv.z), off);
                float op2x = __fadd_rn(fmaxf(ax1_0, Bv.x), off);
                float iw = fmaxf(op1x - op2x, 0.0f);
                float op1y = __fadd_rn(fminf(ay2_0, Bv.w), off);
                float op2y = __fadd_rn(fmaxf(ay1_0, Bv.y), off);
                float ih = fmaxf(op1y - op2y, 0.0f);
                float inter = iw * ih;
                float denom = areaB + aar_0 - inter + 1e-9f;
                if (inter / denom > NMS_T) conf = true;
            }
            if (64 + lane < nacc && (float)alb_1 == labf) {
                float op1x = __fadd_rn(fminf(ax2_1, Bv.z), off);
                float op2x = __fadd_rn(fmaxf(ax1_1, Bv.x), off);
                float iw = fmaxf(op1x - op2x, 0.0f);
                float op1y = __fadd_rn(fminf(ay2_1, Bv.w), off);
                float op2y = __fadd_rn(fmaxf(ay1_1, Bv.y), off);
                float ih = fmaxf(op1y - op2y, 0.0f);
                float inter = iw * ih;
                float denom = areaB + aar_1 - inter + 1e-9f;
                if (inter / denom > NMS_T) conf = true;
            }
            if (__ballot(conf) == 0ull) {
                if (nacc < 64) {
                    if (lane == nacc) {
                        ax1_0 = Bv.x; ay1_0 = Bv.y; ax2_0 = Bv.z; ay2_0 = Bv.w;
                        aar_0 = areaB; alb_0 = (int)labf; aky_0 = ck;
                    }
                } else {
                    if (lane == nacc - 64) {
                        ax1_1 = Bv.x; ay1_1 = Bv.y; ax2_1 = Bv.z; ay2_1 = Bv.w;
                        aar_1 = areaB; alb_1 = (int)labf; aky_1 = ck;
                    }
                }
                ++nacc;
            }
            Bv = nBv; pk = npk; ck = nck;
        }
        if (lane == 0) s_nacc = nacc;
    }
    __syncthreads();

    // ---- exact fallback: remaining ranks up to MSEL (rare; lazy exact T) ----
    if (s_nacc < KOUT && Bthr != 0ull) {
        u64 T = 0ull;
        if (n > MSEL) T = radix_rank(kb, n, MSEL, hist, &s_sel, &s_gt, tid);

        u64*    fkey  = (u64*)ldsbuf;               // 32 KB (4096)
        float4* fbox  = (float4*)(ldsbuf + 32768);  // 64 KB
        float2* fpack = (float2*)(ldsbuf + 98304);  // 32 KB

        for (int i = tid; i < MSEL; i += TN) fkey[i] = 0ull;
        if (tid == 0) s_cnt = 0;
        __syncthreads();
        for (int i0 = tid; i0 < npad; i0 += TN) {
            bool inb = (i0 < n);
            u64 k = inb ? kb[i0] : 0ull;
            bool pred = inb && (k >= T && k < Bthr);
            u64 mb_ = __ballot(pred);
            int cnt = __popcll(mb_);
            int bp = 0;
            if (lane == 0 && cnt) bp = atomicAdd(&s_cnt, cnt);
            bp = __shfl(bp, 0);
            if (pred) {
                int pos = bp + __popcll(mb_ & lm);
                if (pos < MSEL) fkey[pos] = k;
            }
        }
        __syncthreads();
        int mb2 = s_cnt; if (mb2 > MSEL) mb2 = MSEL;

        for (int kk = 2; kk <= MSEL; kk <<= 1) {
            for (int j = kk >> 1; j > 0; j >>= 1) {
                for (int t = tid; t < MSEL; t += TN) {
                    int l = t ^ j;
                    if (l > t) {
                        u64 a = fkey[t], c = fkey[l];
                        bool up = ((t & kk) == 0);
                        bool sw = up ? (a < c) : (a > c);
                        if (sw) { fkey[t] = c; fkey[l] = a; }
                    }
                }
                __syncthreads();
            }
        }

        for (int i = tid; i < mb2; i += TN) {
            u64 k = fkey[i];
            float4 bx; float2 pk;
            DECODE_BODY(k, b, bx, pk);
            fbox[i] = bx;
            fpack[i] = pk;
        }
        __syncthreads();

        if (wid == 0) {
            float4 Bv = fbox[0];
            float2 pk = fpack[0];
            u64    ck = fkey[0];
            for (int i = 0; i < mb2 && nacc < KOUT; ++i) {
                int ip = (i + 1 < mb2) ? i + 1 : i;
                float4 nBv = fbox[ip];
                float2 npk = fpack[ip];
                u64    nck = fkey[ip];

                float areaB = pk.x;
                float labf  = pk.y;
                float off   = __fmul_rn(labf, OFFSETF);
                bool conf = false;
                if (lane < nacc && (float)alb_0 == labf) {
                    float op1x = __fadd_rn(fminf(ax2_0, Bv.z), off);
                    float op2x = __fadd_rn(fmaxf(ax1_0, Bv.x), off);
                    float iw = fmaxf(op1x - op2x, 0.0f);
                    float op1y = __fadd_rn(fminf(ay2_0, Bv.w), off);
                    float op2y = __fadd_rn(fmaxf(ay1_0, Bv.y), off);
                    float ih = fmaxf(op1y - op2y, 0.0f);
                    float inter = iw * ih;
                    float denom = areaB + aar_0 - inter + 1e-9f;
                    if (inter / denom > NMS_T) conf = true;
                }
                if (64 + lane < nacc && (float)alb_1 == labf) {
                    float op1x = __fadd_rn(fminf(ax2_1, Bv.z), off);
                    float op2x = __fadd_rn(fmaxf(ax1_1, Bv.x), off);
                    float iw = fmaxf(op1x - op2x, 0.0f);
                    float op1y = __fadd_rn(fminf(ay2_1, Bv.w), off);
                    float op2y = __fadd_rn(fmaxf(ay1_1, Bv.y), off);
                    float ih = fmaxf(op1y - op2y, 0.0f);
                    float inter = iw * ih;
                    float denom = areaB + aar_1 - inter + 1e-9f;
                    if (inter / denom > NMS_T) conf = true;
                }
                if (__ballot(conf) == 0ull) {
                    if (nacc < 64) {
                        if (lane == nacc) {
                            ax1_0 = Bv.x; ay1_0 = Bv.y; ax2_0 = Bv.z; ay2_0 = Bv.w;
                            aar_0 = areaB; alb_0 = (int)labf; aky_0 = ck;
                        }
                    } else {
                        if (lane == nacc - 64) {
                            ax1_1 = Bv.x; ay1_1 = Bv.y; ax2_1 = Bv.z; ay2_1 = Bv.w;
                            aar_1 = areaB; alb_1 = (int)labf; aky_1 = ck;
                        }
                    }
                    ++nacc;
                }
                Bv = nBv; pk = npk; ck = nck;
            }
            if (lane == 0) s_nacc = nacc;
        }
        __syncthreads();
    }

    // ---- emit outputs in acceptance order (round-8..16 verified) ----
    int na = s_nacc; if (na > KOUT) na = KOUT;
    if (wid == 0) {
        if (lane < na) {
            int a = lane;
            float* ob = out + ((long)b * KOUT + a) * 4;
            ob[0] = ax1_0; ob[1] = ay1_0; ob[2] = ax2_0; ob[3] = ay2_0;
            out[BDIM * KOUT * 4 + b * KOUT + a] = __uint_as_float((u32)(aky_0 >> 32));
            out[BDIM * KOUT * 5 + b * KOUT + a] = (float)alb_0;
            out[BDIM * KOUT * 6 + b * KOUT + a] = 1.0f;
        }
        if (64 + lane < na) {
            int a = 64 + lane;
            float* ob = out + ((long)b * KOUT + a) * 4;
            ob[0] = ax1_1; ob[1] = ay1_1; ob[2] = ax2_1; ob[3] = ay2_1;
            out[BDIM * KOUT * 4 + b * KOUT + a] = __uint_as_float((u32)(aky_1 >> 32));
            out[BDIM * KOUT * 5 + b * KOUT + a] = (float)alb_1;
            out[BDIM * KOUT * 6 + b * KOUT + a] = 1.0f;
        }
    }
    for (int a = tid; a < KOUT; a += TN) {
        if (a >= na) {
            float* ob = out + ((long)b * KOUT + a) * 4;
            ob[0] = 0.0f; ob[1] = 0.0f; ob[2] = 0.0f; ob[3] = 0.0f;
            out[BDIM * KOUT * 4 + b * KOUT + a] = 0.0f;
            out[BDIM * KOUT * 5 + b * KOUT + a] = -1.0f;
            out[BDIM * KOUT * 6 + b * KOUT + a] = 0.0f;
        }
    }
}

extern "C" void kernel_launch(void* const* d_in, const int* in_sizes, int n_in,
                              void* d_out, int out_size, void* d_ws, size_t ws_size,
                              hipStream_t stream) {
    const float* logits = (const float*)d_in[0];
    const float* boxreg = (const float*)d_in[1];
    const float* props  = (const float*)d_in[2];
    float* out = (float*)d_out;

    char* ws = (char*)d_ws;
    int* gcount = (int*)(ws + 0);                 // 64 B
    int* hcnt   = (int*)(ws + 256);               // 64 B
    int* ghist  = (int*)(ws + 1024);              // 16*2048*4 = 128 KB
    u64* hot    = (u64*)(ws + 132096);            // 16*4096*8 = 512 KB
    u64* dense  = (u64*)(ws + 1048576);           // 16*77824*8 = 9.96 MB

    k_zero<<<17, 1024, 0, stream>>>(gcount, hcnt, ghist);
    k_soft<<<(BDIM * NP) / RPB, 256, 0, stream>>>(logits, dense, gcount, hot, hcnt, ghist);
    k_post<<<BDIM, TN, 0, stream>>>(dense, gcount, hot, hcnt, ghist, boxreg, props, out);
}